// Round 4
// baseline (281.298 us; speedup 1.0000x reference)
//
#include <hip/hip_runtime.h>

#define SEQ   4096
#define EMBED 256
#define HEADS 8
#define HDIM  32
#define BH    16      // B * HEADS
#define NROW  8192    // B * SEQ

typedef __bf16 bf16;
typedef bf16  bf16x8 __attribute__((ext_vector_type(8)));
typedef bf16  bf16x4 __attribute__((ext_vector_type(4)));
typedef float f32x4  __attribute__((ext_vector_type(4)));

static __device__ __forceinline__ bf16x4 cvt4(float4 v) {
  bf16x4 r;
  r.x = (bf16)v.x; r.y = (bf16)v.y; r.z = (bf16)v.z; r.w = (bf16)v.w;
  return r;
}

static __device__ __forceinline__ float fast_exp2(float x) {
  float r;
  asm volatile("v_exp_f32 %0, %1" : "=v"(r) : "v"(x));
  return r;
}

// ---------------------------------------------------------------------------
// Merged QKV projection (grid.y selects q/k/v).  Unchanged.
//   z=0: qh[bh][l][d] = rope(q @ Wq^T + bq) * qscale
//   z=1: kh[bh][l][d] = rope(k @ Wk^T + bk)
//   z=2: vt[bh][d][l] = (v @ Wv^T + bv)   (transposed for attn B-frags)
// ---------------------------------------------------------------------------
__global__ __launch_bounds__(256) void proj_kernel(
    const float* __restrict__ qx, const float* __restrict__ kx, const float* __restrict__ vx,
    const float* __restrict__ Wq, const float* __restrict__ bq,
    const float* __restrict__ Wk, const float* __restrict__ bk,
    const float* __restrict__ Wv, const float* __restrict__ bv,
    bf16* __restrict__ qh, bf16* __restrict__ kh, bf16* __restrict__ vt,
    float qscale)
{
  __shared__ alignas(16) bf16 As[64][72];
  __shared__ alignas(16) bf16 Bs[64][72];
  const int z = blockIdx.z;
  const float* X    = (z == 0) ? qx : (z == 1) ? kx : vx;
  const float* W    = (z == 0) ? Wq : (z == 1) ? Wk : Wv;
  const float* bias = (z == 0) ? bq : (z == 1) ? bk : bv;

  const int tid  = threadIdx.x;
  const int wave = tid >> 6;
  const int lane = tid & 63;
  const int quad = lane >> 4;
  const int l16  = lane & 15;
  const int row0 = blockIdx.x * 64;
  const int col0 = blockIdx.y * 64;

  f32x4 acc[4] = { {0.f,0.f,0.f,0.f},{0.f,0.f,0.f,0.f},
                   {0.f,0.f,0.f,0.f},{0.f,0.f,0.f,0.f} };

  for (int k0 = 0; k0 < EMBED; k0 += 64) {
#pragma unroll
    for (int p = 0; p < 4; ++p) {
      int f = p * 256 + tid;          // float4 index, 1024 total
      int r = f >> 4;
      int c = (f & 15) * 4;
      float4 av = *(const float4*)&X[(size_t)(row0 + r) * EMBED + k0 + c];
      *(bf16x4*)&As[r][c] = cvt4(av);
      float4 wv = *(const float4*)&W[(size_t)(col0 + r) * EMBED + k0 + c];
      *(bf16x4*)&Bs[r][c] = cvt4(wv);
    }
    __syncthreads();
#pragma unroll
    for (int kk = 0; kk < 2; ++kk) {
      bf16x8 a = *(const bf16x8*)&As[wave * 16 + l16][kk * 32 + quad * 8];
#pragma unroll
      for (int nt = 0; nt < 4; ++nt) {
        bf16x8 b = *(const bf16x8*)&Bs[nt * 16 + l16][kk * 32 + quad * 8];
        acc[nt] = __builtin_amdgcn_mfma_f32_16x16x32_bf16(a, b, acc[nt], 0, 0, 0);
      }
    }
    __syncthreads();
  }

  if (z < 2) {
    bf16* dst = z ? kh : qh;
    const float out_scale = z ? 1.0f : qscale;
#pragma unroll
    for (int nt = 0; nt < 4; ++nt) {
#pragma unroll
      for (int r = 0; r < 4; ++r) {
        int row = row0 + wave * 16 + quad * 4 + r;   // n = b*SEQ + l
        int col = col0 + nt * 16 + l16;              // e = h*32 + d
        float val = acc[nt][r] + bias[col];
        int l = row & (SEQ - 1);
        {
          float other = __shfl_xor(val, 1);          // partner holds d^1
          int d = col & (HDIM - 1);
          int j = d >> 1;                            // freq index 0..15
          float fr = exp2f(-1.6609640474436813f * (float)(j & 7));
          float t  = (j < 8) ? (float)(l & 63) : (float)(l >> 6);
          float ang = t * fr;
          float sv, cv;
          sincosf(ang, &sv, &cv);
          val = (col & 1) ? (other * sv + val * cv) : (val * cv - other * sv);
        }
        val *= out_scale;
        int b = row >> 12;
        int h = col >> 5;
        int d = col & (HDIM - 1);
        dst[((size_t)((b * HEADS + h) * SEQ + l)) * HDIM + d] = (bf16)val;
      }
    }
  } else {
    // V epilogue: bias, LDS transpose (reuse As), write vt[bh][d][l]
#pragma unroll
    for (int nt = 0; nt < 4; ++nt) {
      float bcol = bias[col0 + nt * 16 + l16];
      bf16x4 pk;
      pk.x = (bf16)(acc[nt][0] + bcol);
      pk.y = (bf16)(acc[nt][1] + bcol);
      pk.z = (bf16)(acc[nt][2] + bcol);
      pk.w = (bf16)(acc[nt][3] + bcol);
      *(bf16x4*)&As[nt * 16 + l16][wave * 16 + quad * 4] = pk;
    }
    __syncthreads();
    const int e   = tid >> 2;           // 0..63 (col within tile)
    const int seg = tid & 3;            // 16-l chunk
    const int ge  = col0 + e;
    const int hh  = ge >> 5;
    const int d   = ge & (HDIM - 1);
    const int bidx = row0 >> 12;
    const int l0   = row0 & (SEQ - 1);
    size_t dstbase = ((size_t)(bidx * HEADS + hh) * HDIM + d) * SEQ + l0 + seg * 16;
    bf16x8 t0 = *(const bf16x8*)&As[e][seg * 16];
    bf16x8 t1 = *(const bf16x8*)&As[e][seg * 16 + 8];
    *(bf16x8*)&vt[dstbase]     = t0;
    *(bf16x8*)&vt[dstbase + 8] = t1;
  }
}

// ---------------------------------------------------------------------------
// Flash attention v5 — BISECT of v4's failure.
//  Exactly the round-0 (verified-passing) v3 body; the ONLY change is
//  __launch_bounds__(512, 8) -> (512, 4).
//  Theory: v3's (512,8) bound forced VGPR=32, which cannot hold the 8
//  per-iteration load destinations (kf0-3 + vf0-3 = 32 VGPRs) at once, so
//  the compiler serialized the loads into ~8 back-to-back L2 latencies per
//  64-key tile (MfmaUtil 7%).  With a 128-VGPR budget the compiler can issue
//  all 8 loads before the first consumer wait -> ~1 exposed latency/iter.
//  Occupancy drops 8->4 waves/SIMD (VGPR steps at 64/128: any alloc in
//  (64,128] gives 4/SIMD), which 16 waves/CU still covers.
//  The v4 cross-iteration register prefetch is REMOVED pending evidence:
//  it miscompiled (absmax 0.49/0.61) even with full ordering fences.
// ---------------------------------------------------------------------------
__global__ __launch_bounds__(512, 4) void attn_kernel(
    const bf16* __restrict__ Q, const bf16* __restrict__ K,
    const bf16* __restrict__ Vt, bf16* __restrict__ H)
{
  __shared__ alignas(16) bf16  Pa[8][16][72];   // per-wave P tile [q][key]
  __shared__ alignas(16) float Cb[4][64][9];    // combine buffer per q-tile

  const int tid  = threadIdx.x;
  const int wave = tid >> 6;
  const int lane = tid & 63;
  const int quad = lane >> 4;
  const int l16  = lane & 15;
  const int wq   = wave & 3;          // q-tile slot within block
  const int half = wave >> 2;         // key half

  const int id   = blockIdx.x;
  const int bh   = ((id & 7) << 1) | (id >> 9);       // XCD-local heads
  const int q0   = ((id >> 3) & 63) * 64 + wq * 16;   // this wave's 16 q rows

  const bf16* Qg = Q  + (size_t)bh * SEQ * HDIM;
  const bf16* Kg = K  + (size_t)bh * SEQ * HDIM;
  const bf16* Vg = Vt + (size_t)bh * HDIM * SEQ;

  // Q fragment (B-operand): n = l16 (q row), k = quad*8+j (dim)
  bf16x8 qf = *(const bf16x8*)&Qg[(size_t)(q0 + l16) * HDIM + quad * 8];

  f32x4 o0 = {0.f,0.f,0.f,0.f};
  f32x4 o1 = {0.f,0.f,0.f,0.f};
  float lsum = 0.f;

  const bf16* kbase  = &Kg[(size_t)l16 * HDIM + quad * 8];
  const bf16* v0base = &Vg[(size_t)l16        * SEQ + quad * 8];
  const bf16* v1base = &Vg[(size_t)(16 + l16) * SEQ + quad * 8];

  const f32x4 minit = {-12.f,-12.f,-12.f,-12.f};   // fixed softmax max
  const int kstart = half * (SEQ / 2);
  const int kend   = kstart + SEQ / 2;

  for (int k0 = kstart; k0 < kend; k0 += 64) {
    // ---- K fragments straight from global (L2-resident) ----
    bf16x8 kf0 = *(const bf16x8*)&kbase[(size_t)(k0 +  0) * HDIM];
    bf16x8 kf1 = *(const bf16x8*)&kbase[(size_t)(k0 + 16) * HDIM];
    bf16x8 kf2 = *(const bf16x8*)&kbase[(size_t)(k0 + 32) * HDIM];
    bf16x8 kf3 = *(const bf16x8*)&kbase[(size_t)(k0 + 48) * HDIM];

    // ---- S^T = K Q^T - 12 : col = q (l16), rows = 4 consecutive keys ----
    f32x4 s[4];
    s[0] = __builtin_amdgcn_mfma_f32_16x16x32_bf16(kf0, qf, minit, 0, 0, 0);
    s[1] = __builtin_amdgcn_mfma_f32_16x16x32_bf16(kf1, qf, minit, 0, 0, 0);
    s[2] = __builtin_amdgcn_mfma_f32_16x16x32_bf16(kf2, qf, minit, 0, 0, 0);
    s[3] = __builtin_amdgcn_mfma_f32_16x16x32_bf16(kf3, qf, minit, 0, 0, 0);

    // ---- V^T fragments (latency overlapped with exp/pack below) ----
    bf16x8 vf0 = *(const bf16x8*)&v0base[k0];
    bf16x8 vf1 = *(const bf16x8*)&v0base[k0 + 32];
    bf16x8 vf2 = *(const bf16x8*)&v1base[k0];
    bf16x8 vf3 = *(const bf16x8*)&v1base[k0 + 32];

    // ---- softmax numerators + packed P store + per-lane row-sum ----
#pragma unroll
    for (int nt = 0; nt < 4; ++nt) {
      float p0 = fast_exp2(s[nt][0]);
      float p1 = fast_exp2(s[nt][1]);
      float p2 = fast_exp2(s[nt][2]);
      float p3 = fast_exp2(s[nt][3]);
      lsum += (p0 + p1) + (p2 + p3);
      bf16x4 pk;
      pk.x = (bf16)p0; pk.y = (bf16)p1; pk.z = (bf16)p2; pk.w = (bf16)p3;
      *(bf16x4*)&Pa[wave][l16][nt * 16 + quad * 4] = pk;   // ds_write_b64
    }

    // wave-internal LDS round trip (DS in-order per wave; drain before read)
    asm volatile("s_waitcnt lgkmcnt(0)" ::: "memory");

    // ---- O += P V : A = P[q][key], B = V^T[d][key] ----
    bf16x8 pf0 = *(const bf16x8*)&Pa[wave][l16][quad * 8];
    bf16x8 pf1 = *(const bf16x8*)&Pa[wave][l16][32 + quad * 8];
    o0 = __builtin_amdgcn_mfma_f32_16x16x32_bf16(pf0, vf0, o0, 0, 0, 0);
    o0 = __builtin_amdgcn_mfma_f32_16x16x32_bf16(pf1, vf1, o0, 0, 0, 0);
    o1 = __builtin_amdgcn_mfma_f32_16x16x32_bf16(pf0, vf2, o1, 0, 0, 0);
    o1 = __builtin_amdgcn_mfma_f32_16x16x32_bf16(pf1, vf3, o1, 0, 0, 0);
  }

  // ---- reduce row-sums across quads (linear, so pre-combine is fine) ----
  lsum += __shfl_xor(lsum, 16);
  lsum += __shfl_xor(lsum, 32);        // every lane: this half's total for q=l16

  // ---- combine the two key-halves through LDS ----
  if (half == 1) {
#pragma unroll
    for (int r = 0; r < 4; ++r) {
      Cb[wq][lane][r]     = o0[r];
      Cb[wq][lane][4 + r] = o1[r];
    }
    Cb[wq][lane][8] = lsum;
  }
  __syncthreads();
  if (half == 0) {
#pragma unroll
    for (int r = 0; r < 4; ++r) {
      o0[r] += Cb[wq][lane][r];
      o1[r] += Cb[wq][lane][4 + r];
    }
    lsum += Cb[wq][lane][8];

    const int b = bh >> 3;
    const int h = bh & 7;
#pragma unroll
    for (int r = 0; r < 4; ++r) {
      float tot  = __shfl(lsum, quad * 4 + r);   // lane with l16 == quad*4+r
      float invr = 1.0f / tot;
      int   qg   = q0 + quad * 4 + r;
      size_t base = ((size_t)(b * SEQ + qg)) * EMBED + h * HDIM;
      H[base + l16]      = (bf16)(o0[r] * invr);
      H[base + 16 + l16] = (bf16)(o1[r] * invr);
    }
  }
}

// ---------------------------------------------------------------------------
// Output projection: out = H @ Wo^T + bo   (fp32 out)  — unchanged
// ---------------------------------------------------------------------------
__global__ __launch_bounds__(256) void out_proj_kernel(
    const bf16* __restrict__ Hm, const float* __restrict__ W,
    const float* __restrict__ bias, float* __restrict__ out)
{
  __shared__ alignas(16) bf16 As[64][72];
  __shared__ alignas(16) bf16 Bs[64][72];
  const int tid  = threadIdx.x;
  const int wave = tid >> 6;
  const int lane = tid & 63;
  const int quad = lane >> 4;
  const int l16  = lane & 15;
  const int row0 = blockIdx.x * 64;
  const int col0 = blockIdx.y * 64;

  f32x4 acc[4] = { {0.f,0.f,0.f,0.f},{0.f,0.f,0.f,0.f},
                   {0.f,0.f,0.f,0.f},{0.f,0.f,0.f,0.f} };

  for (int k0 = 0; k0 < EMBED; k0 += 64) {
#pragma unroll
    for (int p = 0; p < 2; ++p) {       // A: bf16 loads
      int f = p * 256 + tid;
      int r = f >> 3;
      int c = (f & 7) * 8;
      *(bf16x8*)&As[r][c] = *(const bf16x8*)&Hm[(size_t)(row0 + r) * EMBED + k0 + c];
    }
#pragma unroll
    for (int p = 0; p < 4; ++p) {       // B: fp32 -> bf16
      int f = p * 256 + tid;
      int r = f >> 4;
      int c = (f & 15) * 4;
      float4 wv = *(const float4*)&W[(size_t)(col0 + r) * EMBED + k0 + c];
      *(bf16x4*)&Bs[r][c] = cvt4(wv);
    }
    __syncthreads();
#pragma unroll
    for (int kk = 0; kk < 2; ++kk) {
      bf16x8 a = *(const bf16x8*)&As[wave * 16 + l16][kk * 32 + quad * 8];
#pragma unroll
      for (int nt = 0; nt < 4; ++nt) {
        bf16x8 b = *(const bf16x8*)&Bs[nt * 16 + l16][kk * 32 + quad * 8];
        acc[nt] = __builtin_amdgcn_mfma_f32_16x16x32_bf16(a, b, acc[nt], 0, 0, 0);
      }
    }
    __syncthreads();
  }

#pragma unroll
  for (int nt = 0; nt < 4; ++nt) {
#pragma unroll
    for (int r = 0; r < 4; ++r) {
      int row = row0 + wave * 16 + quad * 4 + r;
      int col = col0 + nt * 16 + l16;
      out[(size_t)row * EMBED + col] = acc[nt][r] + bias[col];
    }
  }
}

// ---------------------------------------------------------------------------
extern "C" void kernel_launch(void* const* d_in, const int* in_sizes, int n_in,
                              void* d_out, int out_size, void* d_ws, size_t ws_size,
                              hipStream_t stream) {
  (void)in_sizes; (void)n_in; (void)out_size; (void)ws_size;
  const float* q  = (const float*)d_in[0];
  const float* k  = (const float*)d_in[1];
  const float* v  = (const float*)d_in[2];
  const float* Wq = (const float*)d_in[3];
  const float* bq = (const float*)d_in[4];
  const float* Wk = (const float*)d_in[5];
  const float* bk = (const float*)d_in[6];
  const float* Wv = (const float*)d_in[7];
  const float* bv = (const float*)d_in[8];
  const float* Wo = (const float*)d_in[9];
  const float* bo = (const float*)d_in[10];
  float* out = (float*)d_out;

  const size_t headElems = (size_t)BH * SEQ * HDIM;   // 2,097,152
  bf16* qh = (bf16*)d_ws;
  bf16* kh = qh + headElems;
  bf16* vt = kh + headElems;                          // [BH][HDIM][SEQ]
  bf16* Hm = vt + headElems;                          // [8192][256]

  // Q pre-scale: (1/sqrt(32)) * log2(e) -> softmax in exp2 domain.
  const float qs = 0.2550436604f;

  proj_kernel<<<dim3(128, 4, 3), dim3(256), 0, stream>>>(q, k, v, Wq, bq, Wk, bk,
                                                         Wv, bv, qh, kh, vt, qs);
  attn_kernel<<<dim3(1024), dim3(512), 0, stream>>>(qh, kh, vt, Hm);
  out_proj_kernel<<<dim3(128, 4), dim3(256), 0, stream>>>(Hm, Wo, bo, out);
}

// Round 7
// 173.336 us; speedup vs baseline: 1.6228x; 1.6228x over previous
//
#include <hip/hip_runtime.h>

#define SEQ   4096
#define EMBED 256
#define HEADS 8
#define HDIM  32
#define BH    16      // B * HEADS
#define NROW  8192    // B * SEQ

typedef __bf16 bf16;
typedef bf16  bf16x8 __attribute__((ext_vector_type(8)));
typedef bf16  bf16x4 __attribute__((ext_vector_type(4)));
typedef float f32x4  __attribute__((ext_vector_type(4)));

static __device__ __forceinline__ bf16x4 cvt4(float4 v) {
  bf16x4 r;
  r.x = (bf16)v.x; r.y = (bf16)v.y; r.z = (bf16)v.z; r.w = (bf16)v.w;
  return r;
}

static __device__ __forceinline__ float fast_exp2(float x) {
  float r;
  asm volatile("v_exp_f32 %0, %1" : "=v"(r) : "v"(x));
  return r;
}

// ---------------------------------------------------------------------------
// Merged QKV projection (grid.y selects q/k/v).  Unchanged (verified).
//   z=0: qh[bh][l][d] = rope(q @ Wq^T + bq) * qscale
//   z=1: kh[bh][l][d] = rope(k @ Wk^T + bk)
//   z=2: vt[bh][d][l] = (v @ Wv^T + bv)   (transposed for attn B-frags)
// ---------------------------------------------------------------------------
__global__ __launch_bounds__(256) void proj_kernel(
    const float* __restrict__ qx, const float* __restrict__ kx, const float* __restrict__ vx,
    const float* __restrict__ Wq, const float* __restrict__ bq,
    const float* __restrict__ Wk, const float* __restrict__ bk,
    const float* __restrict__ Wv, const float* __restrict__ bv,
    bf16* __restrict__ qh, bf16* __restrict__ kh, bf16* __restrict__ vt,
    float qscale)
{
  __shared__ alignas(16) bf16 As[64][72];
  __shared__ alignas(16) bf16 Bs[64][72];
  const int z = blockIdx.z;
  const float* X    = (z == 0) ? qx : (z == 1) ? kx : vx;
  const float* W    = (z == 0) ? Wq : (z == 1) ? Wk : Wv;
  const float* bias = (z == 0) ? bq : (z == 1) ? bk : bv;

  const int tid  = threadIdx.x;
  const int wave = tid >> 6;
  const int lane = tid & 63;
  const int quad = lane >> 4;
  const int l16  = lane & 15;
  const int row0 = blockIdx.x * 64;
  const int col0 = blockIdx.y * 64;

  f32x4 acc[4] = { {0.f,0.f,0.f,0.f},{0.f,0.f,0.f,0.f},
                   {0.f,0.f,0.f,0.f},{0.f,0.f,0.f,0.f} };

  for (int k0 = 0; k0 < EMBED; k0 += 64) {
#pragma unroll
    for (int p = 0; p < 4; ++p) {
      int f = p * 256 + tid;          // float4 index, 1024 total
      int r = f >> 4;
      int c = (f & 15) * 4;
      float4 av = *(const float4*)&X[(size_t)(row0 + r) * EMBED + k0 + c];
      *(bf16x4*)&As[r][c] = cvt4(av);
      float4 wv = *(const float4*)&W[(size_t)(col0 + r) * EMBED + k0 + c];
      *(bf16x4*)&Bs[r][c] = cvt4(wv);
    }
    __syncthreads();
#pragma unroll
    for (int kk = 0; kk < 2; ++kk) {
      bf16x8 a = *(const bf16x8*)&As[wave * 16 + l16][kk * 32 + quad * 8];
#pragma unroll
      for (int nt = 0; nt < 4; ++nt) {
        bf16x8 b = *(const bf16x8*)&Bs[nt * 16 + l16][kk * 32 + quad * 8];
        acc[nt] = __builtin_amdgcn_mfma_f32_16x16x32_bf16(a, b, acc[nt], 0, 0, 0);
      }
    }
    __syncthreads();
  }

  if (z < 2) {
    bf16* dst = z ? kh : qh;
    const float out_scale = z ? 1.0f : qscale;
#pragma unroll
    for (int nt = 0; nt < 4; ++nt) {
#pragma unroll
      for (int r = 0; r < 4; ++r) {
        int row = row0 + wave * 16 + quad * 4 + r;   // n = b*SEQ + l
        int col = col0 + nt * 16 + l16;              // e = h*32 + d
        float val = acc[nt][r] + bias[col];
        int l = row & (SEQ - 1);
        {
          float other = __shfl_xor(val, 1);          // partner holds d^1
          int d = col & (HDIM - 1);
          int j = d >> 1;                            // freq index 0..15
          float fr = exp2f(-1.6609640474436813f * (float)(j & 7));
          float t  = (j < 8) ? (float)(l & 63) : (float)(l >> 6);
          float ang = t * fr;
          float sv, cv;
          sincosf(ang, &sv, &cv);
          val = (col & 1) ? (other * sv + val * cv) : (val * cv - other * sv);
        }
        val *= out_scale;
        int b = row >> 12;
        int h = col >> 5;
        int d = col & (HDIM - 1);
        dst[((size_t)((b * HEADS + h) * SEQ + l)) * HDIM + d] = (bf16)val;
      }
    }
  } else {
    // V epilogue: bias, LDS transpose (reuse As), write vt[bh][d][l]
#pragma unroll
    for (int nt = 0; nt < 4; ++nt) {
      float bcol = bias[col0 + nt * 16 + l16];
      bf16x4 pk;
      pk.x = (bf16)(acc[nt][0] + bcol);
      pk.y = (bf16)(acc[nt][1] + bcol);
      pk.z = (bf16)(acc[nt][2] + bcol);
      pk.w = (bf16)(acc[nt][3] + bcol);
      *(bf16x4*)&As[nt * 16 + l16][wave * 16 + quad * 4] = pk;
    }
    __syncthreads();
    const int e   = tid >> 2;           // 0..63 (col within tile)
    const int seg = tid & 3;            // 16-l chunk
    const int ge  = col0 + e;
    const int hh  = ge >> 5;
    const int d   = ge & (HDIM - 1);
    const int bidx = row0 >> 12;
    const int l0   = row0 & (SEQ - 1);
    size_t dstbase = ((size_t)(bidx * HEADS + hh) * HDIM + d) * SEQ + l0 + seg * 16;
    bf16x8 t0 = *(const bf16x8*)&As[e][seg * 16];
    bf16x8 t1 = *(const bf16x8*)&As[e][seg * 16 + 8];
    *(bf16x8*)&vt[dstbase]     = t0;
    *(bf16x8*)&vt[dstbase + 8] = t1;
  }
}

// ---------------------------------------------------------------------------
// Flash attention v8 — cooperative LDS staging (canonical barrier pipeline).
//  Diagnosis: v3/v5 are L1/L2 TRAFFIC bound: within a block every wave of a
//  key-half loads the SAME K/V tiles -> 2 GB of cache reads per dispatch
//  (11.6 TB/s), so time ~ bytes/BW regardless of VGPR/prefetch (neutral v5).
//  Prefetch-window variants (v4/v4.1/v6/v7) all miscompiled; quarantined.
//  NEW STRUCTURE:
//   - Block = 1 head x 128 q-rows (8 waves x 16 rows), sweeping the FULL key
//     range.  No half-split -> no Cb combine.  Grid 512 blocks (2/CU).
//   - Each 64-key K/V tile staged ONCE into LDS, double-buffered, ONE
//     __syncthreads per tile.  8x less global K/V traffic (2 GB -> 256 MB).
//   - T14 split: issue next tile's global load FIRST, compute current tile
//     from LDS, ds_write the staged data LAST, then barrier.
//   - Fragment-major LDS layout Ks/Vs[buf][4][64][8]: each lane reads
//     base+lane*16 -> perfectly linear ds_read_b128, zero bank conflicts.
//   - Pa P-tile round-trip: TEXTUALLY IDENTICAL to verified v3/v5, and now
//     additionally protected by the per-iteration barrier (a real compiler
//     memory fence), which forbids the cross-iteration LDS reordering that
//     plagued the prefetch variants.
// ---------------------------------------------------------------------------
__global__ __launch_bounds__(512, 4) void attn_kernel(
    const bf16* __restrict__ Q, const bf16* __restrict__ K,
    const bf16* __restrict__ Vt, bf16* __restrict__ H)
{
  __shared__ alignas(16) bf16 Ks[2][4][64][8];   // [buf][frag][lane][8]
  __shared__ alignas(16) bf16 Vs[2][4][64][8];   // [buf][frag][lane][8]
  __shared__ alignas(16) bf16 Pa[8][16][72];     // per-wave P tile [q][key]

  const int tid  = threadIdx.x;
  const int wave = tid >> 6;
  const int lane = tid & 63;
  const int quad = lane >> 4;
  const int l16  = lane & 15;

  const int id = blockIdx.x;                     // 0..511
  const int bh = ((id & 7) << 1) | (id >> 8);    // XCD-local heads (2/XCD)
  const int q0 = ((id >> 3) & 31) * 128 + wave * 16;  // wave's 16 q rows

  const bf16* Qg = Q  + (size_t)bh * SEQ * HDIM;
  const bf16* Kg = K  + (size_t)bh * SEQ * HDIM;
  const bf16* Vg = Vt + (size_t)bh * HDIM * SEQ;

  // Q fragment (B-operand): n = l16 (q row), k = quad*8+j (dim)
  bf16x8 qf = *(const bf16x8*)&Qg[(size_t)(q0 + l16) * HDIM + quad * 8];

  f32x4 o0 = {0.f,0.f,0.f,0.f};
  f32x4 o1 = {0.f,0.f,0.f,0.f};
  float lsum = 0.f;

  // ---- staging role: threads 0-255 stage K, 256-511 stage V.
  //      Each thread: one 16B global load + one ds_write_b128 per tile.
  //      K frag n, lane (quad,l16): Kg[(64t + n*16 + l16)*32 + quad*8 ..+8]
  //      V frag f, lane (quad,l16): f = (d>=16)*2 + (key>=32);
  //                                 Vg[d*SEQ + 64t + (key&31) ..] d=16?+l16
  const bool isK = tid < 256;
  const int  tt  = tid & 255;
  const bf16* sbase;
  size_t sstep;
  bf16* d0;
  if (isK) {
    const int r  = tt >> 2;            // key row in tile 0..63
    const int qq = tt & 3;             // dim quarter
    sbase = Kg + (size_t)r * HDIM + qq * 8;
    sstep = (size_t)64 * HDIM;         // next tile: +64 key rows
    d0 = &Ks[0][r >> 4][qq * 16 + (r & 15)][0];
  } else {
    const int d  = tt >> 3;            // dim row 0..31
    const int sg = tt & 7;             // key segment (8 keys)
    sbase = Vg + (size_t)d * SEQ + sg * 8;
    sstep = 64;                        // next tile: +64 keys
    d0 = &Vs[0][((d >> 4) << 1) | (sg >> 2)][(sg & 3) * 16 + (d & 15)][0];
  }
  bf16* d1 = d0 + 4 * 64 * 8;          // buf1 slice of the same array

  const f32x4 minit = {-12.f,-12.f,-12.f,-12.f};   // fixed softmax max

  // ---- prologue: stage tile 0 into buf0 ----
  *(bf16x8*)d0 = *(const bf16x8*)sbase;
  __syncthreads();

  for (int t = 0; t < 64; ++t) {
    const int cur = t & 1;
    const int tn  = (t < 63) ? t + 1 : 63;   // last iter: harmless re-stage
    // ---- T14: issue next-tile global load FIRST (completes under compute)
    bf16x8 g = *(const bf16x8*)&sbase[(size_t)tn * sstep];

    const bf16* KT = &Ks[cur][0][0][0];
    const bf16* VT = &Vs[cur][0][0][0];

    // ---- K fragments from LDS (linear per lane: zero bank conflict) ----
    bf16x8 kf0 = *(const bf16x8*)&KT[(0 * 64 + lane) * 8];
    bf16x8 kf1 = *(const bf16x8*)&KT[(1 * 64 + lane) * 8];
    bf16x8 kf2 = *(const bf16x8*)&KT[(2 * 64 + lane) * 8];
    bf16x8 kf3 = *(const bf16x8*)&KT[(3 * 64 + lane) * 8];

    // ---- S^T = K Q^T - 12 : col = q (l16), rows = 4 consecutive keys ----
    f32x4 s[4];
    s[0] = __builtin_amdgcn_mfma_f32_16x16x32_bf16(kf0, qf, minit, 0, 0, 0);
    s[1] = __builtin_amdgcn_mfma_f32_16x16x32_bf16(kf1, qf, minit, 0, 0, 0);
    s[2] = __builtin_amdgcn_mfma_f32_16x16x32_bf16(kf2, qf, minit, 0, 0, 0);
    s[3] = __builtin_amdgcn_mfma_f32_16x16x32_bf16(kf3, qf, minit, 0, 0, 0);

    // ---- V^T fragments from LDS ----
    bf16x8 vf0 = *(const bf16x8*)&VT[(0 * 64 + lane) * 8];
    bf16x8 vf1 = *(const bf16x8*)&VT[(1 * 64 + lane) * 8];
    bf16x8 vf2 = *(const bf16x8*)&VT[(2 * 64 + lane) * 8];
    bf16x8 vf3 = *(const bf16x8*)&VT[(3 * 64 + lane) * 8];

    // ---- softmax numerators + packed P store + per-lane row-sum ----
    //      (textually identical to the verified v3/v5 round-trip)
#pragma unroll
    for (int nt = 0; nt < 4; ++nt) {
      float p0 = fast_exp2(s[nt][0]);
      float p1 = fast_exp2(s[nt][1]);
      float p2 = fast_exp2(s[nt][2]);
      float p3 = fast_exp2(s[nt][3]);
      lsum += (p0 + p1) + (p2 + p3);
      bf16x4 pk;
      pk.x = (bf16)p0; pk.y = (bf16)p1; pk.z = (bf16)p2; pk.w = (bf16)p3;
      *(bf16x4*)&Pa[wave][l16][nt * 16 + quad * 4] = pk;   // ds_write_b64
    }

    // wave-internal LDS round trip (DS in-order per wave; drain before read)
    asm volatile("s_waitcnt lgkmcnt(0)" ::: "memory");

    // ---- O += P V : A = P[q][key], B = V^T[d][key] ----
    bf16x8 pf0 = *(const bf16x8*)&Pa[wave][l16][quad * 8];
    bf16x8 pf1 = *(const bf16x8*)&Pa[wave][l16][32 + quad * 8];
    o0 = __builtin_amdgcn_mfma_f32_16x16x32_bf16(pf0, vf0, o0, 0, 0, 0);
    o0 = __builtin_amdgcn_mfma_f32_16x16x32_bf16(pf1, vf1, o0, 0, 0, 0);
    o1 = __builtin_amdgcn_mfma_f32_16x16x32_bf16(pf0, vf2, o1, 0, 0, 0);
    o1 = __builtin_amdgcn_mfma_f32_16x16x32_bf16(pf1, vf3, o1, 0, 0, 0);

    // ---- write staged data into the other buffer, then fence the tile ----
    *(bf16x8*)(cur ? d0 : d1) = g;
    __syncthreads();
  }

  // ---- reduce row-sums across quads: lsum(lane) = total for q = l16 ----
  lsum += __shfl_xor(lsum, 16);
  lsum += __shfl_xor(lsum, 32);

  const int b = bh >> 3;
  const int h = bh & 7;
#pragma unroll
  for (int r = 0; r < 4; ++r) {
    float tot  = __shfl(lsum, quad * 4 + r);   // lane with l16 == quad*4+r
    float invr = 1.0f / tot;
    int   qg   = q0 + quad * 4 + r;
    size_t base = ((size_t)(b * SEQ + qg)) * EMBED + h * HDIM;
    H[base + l16]      = (bf16)(o0[r] * invr);
    H[base + 16 + l16] = (bf16)(o1[r] * invr);
  }
}

// ---------------------------------------------------------------------------
// Output projection: out = H @ Wo^T + bo   (fp32 out)  — unchanged
// ---------------------------------------------------------------------------
__global__ __launch_bounds__(256) void out_proj_kernel(
    const bf16* __restrict__ Hm, const float* __restrict__ W,
    const float* __restrict__ bias, float* __restrict__ out)
{
  __shared__ alignas(16) bf16 As[64][72];
  __shared__ alignas(16) bf16 Bs[64][72];
  const int tid  = threadIdx.x;
  const int wave = tid >> 6;
  const int lane = tid & 63;
  const int quad = lane >> 4;
  const int l16  = lane & 15;
  const int row0 = blockIdx.x * 64;
  const int col0 = blockIdx.y * 64;

  f32x4 acc[4] = { {0.f,0.f,0.f,0.f},{0.f,0.f,0.f,0.f},
                   {0.f,0.f,0.f,0.f},{0.f,0.f,0.f,0.f} };

  for (int k0 = 0; k0 < EMBED; k0 += 64) {
#pragma unroll
    for (int p = 0; p < 2; ++p) {       // A: bf16 loads
      int f = p * 256 + tid;
      int r = f >> 3;
      int c = (f & 7) * 8;
      *(bf16x8*)&As[r][c] = *(const bf16x8*)&Hm[(size_t)(row0 + r) * EMBED + k0 + c];
    }
#pragma unroll
    for (int p = 0; p < 4; ++p) {       // B: fp32 -> bf16
      int f = p * 256 + tid;
      int r = f >> 4;
      int c = (f & 15) * 4;
      float4 wv = *(const float4*)&W[(size_t)(col0 + r) * EMBED + k0 + c];
      *(bf16x4*)&Bs[r][c] = cvt4(wv);
    }
    __syncthreads();
#pragma unroll
    for (int kk = 0; kk < 2; ++kk) {
      bf16x8 a = *(const bf16x8*)&As[wave * 16 + l16][kk * 32 + quad * 8];
#pragma unroll
      for (int nt = 0; nt < 4; ++nt) {
        bf16x8 b = *(const bf16x8*)&Bs[nt * 16 + l16][kk * 32 + quad * 8];
        acc[nt] = __builtin_amdgcn_mfma_f32_16x16x32_bf16(a, b, acc[nt], 0, 0, 0);
      }
    }
    __syncthreads();
  }

#pragma unroll
  for (int nt = 0; nt < 4; ++nt) {
#pragma unroll
    for (int r = 0; r < 4; ++r) {
      int row = row0 + wave * 16 + quad * 4 + r;
      int col = col0 + nt * 16 + l16;
      out[(size_t)row * EMBED + col] = acc[nt][r] + bias[col];
    }
  }
}

// ---------------------------------------------------------------------------
extern "C" void kernel_launch(void* const* d_in, const int* in_sizes, int n_in,
                              void* d_out, int out_size, void* d_ws, size_t ws_size,
                              hipStream_t stream) {
  (void)in_sizes; (void)n_in; (void)out_size; (void)ws_size;
  const float* q  = (const float*)d_in[0];
  const float* k  = (const float*)d_in[1];
  const float* v  = (const float*)d_in[2];
  const float* Wq = (const float*)d_in[3];
  const float* bq = (const float*)d_in[4];
  const float* Wk = (const float*)d_in[5];
  const float* bk = (const float*)d_in[6];
  const float* Wv = (const float*)d_in[7];
  const float* bv = (const float*)d_in[8];
  const float* Wo = (const float*)d_in[9];
  const float* bo = (const float*)d_in[10];
  float* out = (float*)d_out;

  const size_t headElems = (size_t)BH * SEQ * HDIM;   // 2,097,152
  bf16* qh = (bf16*)d_ws;
  bf16* kh = qh + headElems;
  bf16* vt = kh + headElems;                          // [BH][HDIM][SEQ]
  bf16* Hm = vt + headElems;                          // [8192][256]

  // Q pre-scale: (1/sqrt(32)) * log2(e) -> softmax in exp2 domain.
  const float qs = 0.2550436604f;

  proj_kernel<<<dim3(128, 4, 3), dim3(256), 0, stream>>>(q, k, v, Wq, bq, Wk, bk,
                                                         Wv, bv, qh, kh, vt, qs);
  attn_kernel<<<dim3(512), dim3(512), 0, stream>>>(qh, kh, vt, Hm);
  out_proj_kernel<<<dim3(128, 4), dim3(256), 0, stream>>>(Hm, Wo, bo, out);
}